// Round 3
// baseline (41.821 us; speedup 1.0000x reference)
//
#include <hip/hip_runtime.h>
#include <math.h>

#define NB 8
#define N_OP 1000
#define N_MA 64
#define IN_DST 64
#define DD 128
#define NEG_SLOPE 0.2f

__device__ __forceinline__ float lrelu(float x) { return x >= 0.f ? x : NEG_SLOPE * x; }

__device__ __forceinline__ float wave_sum(float v) {
    for (int off = 32; off; off >>= 1) v += __shfl_xor(v, off, 64);
    return v;
}

// K_AB: one block per (b, o-tile). Recomputes c_we/u/v/er/el in-block, then
// masked softmax numerators (M=0; logits bounded ~12, safe in f32) and the
// partial contraction S_part[b,ti,m,i] = sum_{o in tile} p[o,m]*h_src[b,o,i].
template <int TILE_O, int NTILE>
__global__ __launch_bounds__(256) void ab_fused(
    const float* __restrict__ h_src, const float* __restrict__ h_dst,
    const float* __restrict__ edge_feat, const int* __restrict__ adj,
    const float* __restrict__ W_src, const float* __restrict__ W_dst,
    const float* __restrict__ W_edge, const float* __restrict__ attn_l,
    const float* __restrict__ attn_r, float* __restrict__ S_part,
    float* __restrict__ zpart, float* __restrict__ separt) {
    __shared__ float H_l[TILE_O][DD];
    __shared__ float P_l[TILE_O][N_MA];
    __shared__ float u_l[DD];
    __shared__ float v_l[IN_DST];
    __shared__ float er_l[N_MA];
    __shared__ float el_l[TILE_O];
    __shared__ float redz[4][N_MA], redse[4][N_MA];

    int blk = blockIdx.x;
    int b = blk / NTILE, ti = blk % NTILE;
    int o0 = ti * TILE_O;
    int nrows = min(TILE_O, N_OP - o0);
    int t = threadIdx.x;
    int lane = t & 63, w = t >> 6;

    // stage H tile (coalesced float4), zero OOB rows
    for (int f = t; f < TILE_O * 32; f += 256) {
        int row = f >> 5, c4 = (f & 31) * 4;
        float4 hv = make_float4(0.f, 0.f, 0.f, 0.f);
        if (row < nrows)
            hv = *reinterpret_cast<const float4*>(
                h_src + ((size_t)(b * N_OP + o0 + row) * DD + c4));
        *reinterpret_cast<float4*>(&H_l[row][c4]) = hv;
    }

    float al0 = attn_l[lane], al1 = attn_l[lane + 64];
    float ar0 = attn_r[lane], ar1 = attn_r[lane + 64];

    // c_we = dot(W_edge, attn_l)  (every lane ends with the value)
    float cwe = wave_sum(W_edge[lane] * al0 + W_edge[lane + 64] * al1);

    // u[i] = dot(W_src[i,:], attn_l): each wave 32 rows, coalesced
    for (int q = 0; q < 32; ++q) {
        int i = w * 32 + q;
        float part = W_src[i * DD + lane] * al0 + W_src[i * DD + lane + 64] * al1;
        part = wave_sum(part);
        if (lane == 0) u_l[i] = part;
    }
    // v[k] = dot(W_dst[k,:], attn_r): each wave 16 rows
    for (int q = 0; q < 16; ++q) {
        int k = w * 16 + q;
        float part = W_dst[k * DD + lane] * ar0 + W_dst[k * DD + lane + 64] * ar1;
        part = wave_sum(part);
        if (lane == 0) v_l[k] = part;
    }
    __syncthreads();  // H_l, u_l, v_l ready

    // er[m] = dot(h_dst[b,m,:], v): 64-elem row == 64 lanes
    for (int q = 0; q < 16; ++q) {
        int m = w * 16 + q;
        float part = h_dst[((size_t)(b * N_MA + m)) * IN_DST + lane] * v_l[lane];
        part = wave_sum(part);
        if (lane == 0) er_l[m] = part;
    }
    // el[r] = dot(H_l[r,:], u)
    for (int r = w; r < TILE_O; r += 4) {
        float part = H_l[r][lane] * u_l[lane] + H_l[r][lane + 64] * u_l[lane + 64];
        part = wave_sum(part);
        if (lane == 0) el_l[r] = part;
    }
    __syncthreads();  // er_l, el_l ready

    // phase 1: p + tile stats (coalesced adj/ef rows)
    int m = lane;
    float er_bm = er_l[m];
    float z = 0.f, se = 0.f;
    for (int r = w; r < TILE_O; r += 4) {
        float p = 0.f;
        if (r < nrows) {
            size_t e = (size_t)(b * N_OP + o0 + r) * N_MA + m;
            if (adj[e]) {
                float ef = edge_feat[e];
                float vv = lrelu(el_l[r] + er_bm + ef * cwe);
                p = __expf(vv);
                z += p;
                se += p * ef;
            }
        }
        P_l[r][m] = p;
    }
    redz[w][m] = z;
    redse[w][m] = se;
    __syncthreads();

    if (t < 64) {
        zpart[ti * 512 + b * N_MA + t] =
            redz[0][t] + redz[1][t] + redz[2][t] + redz[3][t];
    } else if (t < 128) {
        int mm = t - 64;
        separt[ti * 512 + b * N_MA + mm] =
            redse[0][mm] + redse[1][mm] + redse[2][mm] + redse[3][mm];
    }

    // phase 2: S_part[m][i] = sum_k P_l[k][m] * H_l[k][i]
    int i4 = t & 31, mg = t >> 5;
    float acc[8][4];
    #pragma unroll
    for (int a = 0; a < 8; ++a)
        #pragma unroll
        for (int c = 0; c < 4; ++c) acc[a][c] = 0.f;

    for (int k = 0; k < TILE_O; ++k) {
        float4 hv = *reinterpret_cast<const float4*>(&H_l[k][i4 * 4]);
        float4 pa = *reinterpret_cast<const float4*>(&P_l[k][mg * 8]);
        float4 pb = *reinterpret_cast<const float4*>(&P_l[k][mg * 8 + 4]);
        float hh[4] = {hv.x, hv.y, hv.z, hv.w};
        float pp[8] = {pa.x, pa.y, pa.z, pa.w, pb.x, pb.y, pb.z, pb.w};
        #pragma unroll
        for (int mm = 0; mm < 8; ++mm)
            #pragma unroll
            for (int ii = 0; ii < 4; ++ii)
                acc[mm][ii] += pp[mm] * hh[ii];
    }

    #pragma unroll
    for (int mm = 0; mm < 8; ++mm) {
        size_t off = ((size_t)(b * NTILE + ti) * N_MA + mg * 8 + mm) * DD + i4 * 4;
        *reinterpret_cast<float4*>(S_part + off) =
            make_float4(acc[mm][0], acc[mm][1], acc[mm][2], acc[mm][3]);
    }
}

// K_C: per (b,m): reduce tile partials, recompute feat_dst row + er in-block,
// W_src matvec, sigmoid epilogue.
template <int NTILE>
__global__ __launch_bounds__(256) void c_fused(
    const float* __restrict__ S_part, const float* __restrict__ zpart,
    const float* __restrict__ separt, const float* __restrict__ h_dst,
    const float* __restrict__ W_dst, const float* __restrict__ W_src,
    const float* __restrict__ W_edge, const float* __restrict__ attn_r,
    float* __restrict__ out) {
    __shared__ float Sp[2][DD];
    __shared__ float Fp[2][DD];
    __shared__ float Wp[2][DD];
    __shared__ float S_l[DD];
    __shared__ float fd_l[DD];
    __shared__ float hd_l[IN_DST];
    __shared__ float sZ, sSE, sER;

    int bm = blockIdx.x;
    int b = bm >> 6, m = bm & 63;
    int t = threadIdx.x;
    int lane = t & 63, w = t >> 6;
    int i = t & 127, h = t >> 7;

    if (t < IN_DST) hd_l[t] = h_dst[(size_t)bm * IN_DST + t];

    if (w == 0) {
        float vz = (lane < NTILE) ? zpart[lane * 512 + bm] : 0.f;
        vz = wave_sum(vz);
        if (lane == 0) sZ = vz;
    } else if (w == 1) {
        float vs = (lane < NTILE) ? separt[lane * 512 + bm] : 0.f;
        vs = wave_sum(vs);
        if (lane == 0) sSE = vs;
    }

    float ps = 0.f;
    #pragma unroll
    for (int q = 0; q < NTILE / 2; ++q) {
        int ti = h * (NTILE / 2) + q;
        ps += S_part[((size_t)(b * NTILE + ti) * N_MA + m) * DD + i];
    }
    Sp[h][i] = ps;
    __syncthreads();  // hd_l, Sp, stats ready

    if (t < DD) S_l[t] = Sp[0][t] + Sp[1][t];
    float fa = 0.f;
    #pragma unroll 8
    for (int k = h * 32; k < h * 32 + 32; ++k) fa += hd_l[k] * W_dst[k * DD + i];
    Fp[h][i] = fa;
    __syncthreads();  // S_l, Fp ready

    if (t < DD) fd_l[t] = Fp[0][t] + Fp[1][t];
    float acc = 0.f;
    #pragma unroll 8
    for (int q = 0; q < 64; ++q) {
        int ii = h * 64 + q;
        acc += S_l[ii] * W_src[ii * DD + i];
    }
    Wp[h][i] = acc;
    __syncthreads();  // fd_l, Wp ready

    if (w == 0) {
        float e = fd_l[lane] * attn_r[lane] + fd_l[lane + 64] * attn_r[lane + 64];
        e = wave_sum(e);
        if (lane == 0) sER = e;
    }
    __syncthreads();

    if (t < DD) {
        float p_kk = __expf(lrelu(2.f * sER));
        float Z = sZ + p_kk;
        float invZ = 1.f / Z;
        float bsrc = (Wp[0][i] + Wp[1][i]) * invZ;
        float val = W_edge[i] * (sSE * invZ) + bsrc + fd_l[i] * (p_kk * invZ);
        out[(size_t)bm * DD + i] = 1.f / (1.f + __expf(-val));
    }
}

extern "C" void kernel_launch(void* const* d_in, const int* in_sizes, int n_in,
                              void* d_out, int out_size, void* d_ws, size_t ws_size,
                              hipStream_t stream) {
    const float* h_src = (const float*)d_in[0];
    const float* h_dst = (const float*)d_in[1];
    const float* edge_feat = (const float*)d_in[2];
    const int* adj = (const int*)d_in[3];
    const float* W_src = (const float*)d_in[4];
    const float* W_dst = (const float*)d_in[5];
    const float* W_edge = (const float*)d_in[6];
    const float* attn_l = (const float*)d_in[7];
    const float* attn_r = (const float*)d_in[8];
    float* out = (float*)d_out;
    float* ws = (float*)d_ws;

    // preferred: 32 tiles of 32 (256 blocks = 1/CU); fallback to proven 20x50
    const size_t need32 = (size_t)(2 * 32 * 512 + NB * 32 * N_MA * DD) * 4;
    if (ws_size >= need32) {
        float* zpart = ws;
        float* separt = ws + 32 * 512;
        float* S_part = ws + 2 * 32 * 512;
        ab_fused<32, 32><<<NB * 32, 256, 0, stream>>>(
            h_src, h_dst, edge_feat, adj, W_src, W_dst, W_edge, attn_l, attn_r,
            S_part, zpart, separt);
        c_fused<32><<<NB * N_MA, 256, 0, stream>>>(
            S_part, zpart, separt, h_dst, W_dst, W_src, W_edge, attn_r, out);
    } else {
        float* zpart = ws;
        float* separt = ws + 20 * 512;
        float* S_part = ws + 2 * 20 * 512;
        ab_fused<50, 20><<<NB * 20, 256, 0, stream>>>(
            h_src, h_dst, edge_feat, adj, W_src, W_dst, W_edge, attn_l, attn_r,
            S_part, zpart, separt);
        c_fused<20><<<NB * N_MA, 256, 0, stream>>>(
            S_part, zpart, separt, h_dst, W_dst, W_src, W_edge, attn_r, out);
    }
}

// Round 4
// 29.578 us; speedup vs baseline: 1.4139x; 1.4139x over previous
//
#include <hip/hip_runtime.h>
#include <math.h>

#define NB 8
#define N_OP 1000
#define N_MA 64
#define IN_SRC 128
#define IN_DST 64
#define DD 128
#define NEG_SLOPE 0.2f
#define TILE_O 32
#define NTILE 32   // covers 32*32=1024 >= 1000 rows (tail guarded)

__device__ __forceinline__ float lrelu(float x) { return x >= 0.f ? x : NEG_SLOPE * x; }

__device__ __forceinline__ float wave_sum(float v) {
    for (int off = 32; off; off >>= 1) v += __shfl_xor(v, off, 64);
    return v;
}

// K1: one wave per output. tasks 0..127 -> u[i] = dot(W_src[i,:], attn_l);
// task 128 -> c_we = dot(W_edge, attn_l). 33 blocks x 4 waves, all coalesced.
__global__ __launch_bounds__(256) void prep_par(
    const float* __restrict__ W_src, const float* __restrict__ W_edge,
    const float* __restrict__ attn_l, float* __restrict__ u,
    float* __restrict__ c_we) {
    int lane = threadIdx.x & 63;
    int task = blockIdx.x * 4 + (threadIdx.x >> 6);
    float al0 = attn_l[lane], al1 = attn_l[lane + 64];
    if (task < 128) {
        float part = W_src[task * DD + lane] * al0 + W_src[task * DD + lane + 64] * al1;
        part = wave_sum(part);
        if (lane == 0) u[task] = part;
    } else if (task == 128) {
        float part = W_edge[lane] * al0 + W_edge[lane + 64] * al1;
        part = wave_sum(part);
        if (lane == 0) c_we[0] = part;
    }
}

// K2: blocks [0,2000): el rows (4/block); blocks [2000,2128): feat_dst + er
__global__ __launch_bounds__(256) void elfdst_kernel(
    const float* __restrict__ h_src, const float* __restrict__ u,
    const float* __restrict__ h_dst, const float* __restrict__ W_dst,
    const float* __restrict__ attn_r, float* __restrict__ el,
    float* __restrict__ feat_dst, float* __restrict__ er) {
    int blk = blockIdx.x;
    int lane = threadIdx.x & 63;
    int w = threadIdx.x >> 6;
    if (blk < 2000) {
        int row = blk * 4 + w;   // < 8000 always
        const float* h = h_src + (size_t)row * IN_SRC;
        float acc = h[lane] * u[lane] + h[lane + 64] * u[lane + 64];
        acc = wave_sum(acc);
        if (lane == 0) el[row] = acc;
    } else {
        int bm = (blk - 2000) * 4 + w;  // < 512 always
        const float* h = h_dst + (size_t)bm * IN_DST;
        float a0 = 0.f, a1 = 0.f;
        #pragma unroll 8
        for (int k = 0; k < IN_DST; ++k) {
            float hk = h[k];
            a0 += hk * W_dst[k * DD + lane];
            a1 += hk * W_dst[k * DD + lane + 64];
        }
        feat_dst[(size_t)bm * DD + lane] = a0;
        feat_dst[(size_t)bm * DD + lane + 64] = a1;
        float r = a0 * attn_r[lane] + a1 * attn_r[lane + 64];
        r = wave_sum(r);
        if (lane == 0) er[bm] = r;
    }
}

// K3: per (b, o-tile): p = masked exp (M=0; logits bounded ~14, safe in f32),
// tile stats, partial contraction S_part[b,ti,m,i] = sum_o p[o,m]*h_src[b,o,i]
__global__ __launch_bounds__(256) void ab_kernel(
    const float* __restrict__ edge_feat, const int* __restrict__ adj,
    const float* __restrict__ h_src, const float* __restrict__ el,
    const float* __restrict__ er, const float* __restrict__ c_we_p,
    float* __restrict__ S_part, float* __restrict__ zpart,
    float* __restrict__ separt) {
    __shared__ float P_l[TILE_O][N_MA];    // 8 KB
    __shared__ float H_l[TILE_O][DD];      // 16 KB
    __shared__ float redz[4][64], redse[4][64];

    int blk = blockIdx.x;               // 0..255
    int b = blk >> 5, ti = blk & 31;
    int o0 = ti * TILE_O;
    int nrows = min(TILE_O, N_OP - o0); // 32, or 8 for ti==31
    int t = threadIdx.x;
    float cwe = c_we_p[0];

    // stage H tile (coalesced float4); zero OOB rows
    #pragma unroll
    for (int c = 0; c < 4; ++c) {
        int flat = c * 256 + t;          // 1024 float4 slots = 32 rows x 32
        int row = flat >> 5, col = (flat & 31) * 4;
        float4 hv = make_float4(0.f, 0.f, 0.f, 0.f);
        if (row < nrows)
            hv = *reinterpret_cast<const float4*>(
                h_src + ((size_t)(b * N_OP + o0 + row) * DD + col));
        *reinterpret_cast<float4*>(&H_l[row][col]) = hv;
    }

    // phase 1: p + per-tile stats (coalesced adj/ef rows)
    int m = t & 63, og = t >> 6;
    float er_bm = er[b * N_MA + m];
    float z = 0.f, se = 0.f;
    for (int r = og; r < TILE_O; r += 4) {
        float p = 0.f;
        if (r < nrows) {
            int o = o0 + r;
            size_t eidx = (size_t)(b * N_OP + o) * N_MA + m;
            if (adj[eidx]) {
                float efv = edge_feat[eidx];
                float v = lrelu(el[b * N_OP + o] + er_bm + efv * cwe);
                p = __expf(v);
                z += p;
                se += p * efv;
            }
        }
        P_l[r][m] = p;
    }
    redz[og][m] = z;
    redse[og][m] = se;
    __syncthreads();

    if (t < 64) {
        zpart[ti * 512 + b * N_MA + t] =
            redz[0][t] + redz[1][t] + redz[2][t] + redz[3][t];
    } else if (t < 128) {
        int mm = t - 64;
        separt[ti * 512 + b * N_MA + mm] =
            redse[0][mm] + redse[1][mm] + redse[2][mm] + redse[3][mm];
    }

    // phase 2: S_part[m][i] = sum_k P_l[k][m] * H_l[k][i]
    int i4 = t & 31, mg = t >> 5;
    float acc[8][4];
    #pragma unroll
    for (int a = 0; a < 8; ++a)
        #pragma unroll
        for (int c = 0; c < 4; ++c) acc[a][c] = 0.f;

    for (int k = 0; k < TILE_O; ++k) {
        float4 hv = *reinterpret_cast<const float4*>(&H_l[k][i4 * 4]);
        float4 pa = *reinterpret_cast<const float4*>(&P_l[k][mg * 8]);
        float4 pb = *reinterpret_cast<const float4*>(&P_l[k][mg * 8 + 4]);
        float hh[4] = {hv.x, hv.y, hv.z, hv.w};
        float pp[8] = {pa.x, pa.y, pa.z, pa.w, pb.x, pb.y, pb.z, pb.w};
        #pragma unroll
        for (int mm = 0; mm < 8; ++mm)
            #pragma unroll
            for (int ii = 0; ii < 4; ++ii)
                acc[mm][ii] += pp[mm] * hh[ii];
    }

    #pragma unroll
    for (int mm = 0; mm < 8; ++mm) {
        size_t off = ((size_t)(b * NTILE + ti) * N_MA + mg * 8 + mm) * DD + i4 * 4;
        *reinterpret_cast<float4*>(S_part + off) =
            make_float4(acc[mm][0], acc[mm][1], acc[mm][2], acc[mm][3]);
    }
}

// K4: per (b,m): sum partials, matvec with W_src, epilogue sigmoid
__global__ __launch_bounds__(256) void c_kernel(
    const float* __restrict__ S_part, const float* __restrict__ zpart,
    const float* __restrict__ separt, const float* __restrict__ er,
    const float* __restrict__ feat_dst, const float* __restrict__ W_src,
    const float* __restrict__ W_edge, float* __restrict__ out) {
    __shared__ float Sp[2][DD];
    __shared__ float S_l[DD];
    __shared__ float Wp[2][DD];
    __shared__ float sZ, sSE;

    int bm = blockIdx.x;
    int b = bm >> 6, m = bm & 63;
    int t = threadIdx.x;
    int i = t & 127, h = t >> 7;
    int lane = t & 63, w = t >> 6;

    if (w == 0) {
        float v = (lane < NTILE) ? zpart[lane * 512 + bm] : 0.f;
        v = wave_sum(v);
        if (lane == 0) sZ = v;
    } else if (w == 1) {
        float v = (lane < NTILE) ? separt[lane * 512 + bm] : 0.f;
        v = wave_sum(v);
        if (lane == 0) sSE = v;
    }

    // partial sums of S over tiles (coalesced, independent loads)
    float ps = 0.f;
    #pragma unroll
    for (int q = 0; q < NTILE / 2; ++q) {
        int ti = h * (NTILE / 2) + q;
        ps += S_part[((size_t)(b * NTILE + ti) * N_MA + m) * DD + i];
    }
    Sp[h][i] = ps;
    __syncthreads();
    if (t < DD) S_l[t] = Sp[0][t] + Sp[1][t];
    __syncthreads();

    // matvec: bsrc[d] = sum_i S_l[i] * W_src[i,d]
    int d = i;
    float acc = 0.f;
    #pragma unroll 8
    for (int q = 0; q < 64; ++q) {
        int ii = h * 64 + q;
        acc += S_l[ii] * W_src[ii * DD + d];
    }
    Wp[h][d] = acc;
    __syncthreads();

    if (t < DD) {
        float er_bm = er[bm];
        float p_kk = __expf(lrelu(2.f * er_bm));
        float Z = sZ + p_kk;
        float invZ = 1.f / Z;
        float bsrc = (Wp[0][d] + Wp[1][d]) * invZ;
        float val = W_edge[d] * (sSE * invZ) + bsrc +
                    feat_dst[(size_t)bm * DD + d] * (p_kk * invZ);
        out[(size_t)bm * DD + d] = 1.f / (1.f + __expf(-val));
    }
}

extern "C" void kernel_launch(void* const* d_in, const int* in_sizes, int n_in,
                              void* d_out, int out_size, void* d_ws, size_t ws_size,
                              hipStream_t stream) {
    const float* h_src = (const float*)d_in[0];
    const float* h_dst = (const float*)d_in[1];
    const float* edge_feat = (const float*)d_in[2];
    const int* adj = (const int*)d_in[3];
    const float* W_src = (const float*)d_in[4];
    const float* W_dst = (const float*)d_in[5];
    const float* W_edge = (const float*)d_in[6];
    const float* attn_l = (const float*)d_in[7];
    const float* attn_r = (const float*)d_in[8];
    float* out = (float*)d_out;

    float* ws = (float*)d_ws;
    float* u = ws;                     // 128
    float* c_we = ws + 128;            // 1
    float* el = ws + 256;              // 8000
    float* er = ws + 8448;             // 512
    float* feat_dst = ws + 9216;       // 65536
    float* zpart = ws + 75008;         // 32*512 = 16384
    float* separt = ws + 91392;        // 16384
    float* S_part = ws + 107776;       // 8*32*64*128 = 2097152

    prep_par<<<33, 256, 0, stream>>>(W_src, W_edge, attn_l, u, c_we);
    elfdst_kernel<<<2128, 256, 0, stream>>>(h_src, u, h_dst, W_dst, attn_r,
                                            el, feat_dst, er);
    ab_kernel<<<NB * NTILE, 256, 0, stream>>>(edge_feat, adj, h_src, el, er,
                                              c_we, S_part, zpart, separt);
    c_kernel<<<NB * N_MA, 256, 0, stream>>>(S_part, zpart, separt, er,
                                            feat_dst, W_src, W_edge, out);
}